// Round 8
// baseline (300.510 us; speedup 1.0000x reference)
//
#include <hip/hip_runtime.h>
#include <cstdint>

// ---------------------------------------------------------------------------
// RegionModel R20: conv3 single-stage full-K tile + fused setup kernel.
// R19b confirmed (287us): conv12 108us @ 3 blocks/CU (predicted). conv3 is
// now co-largest (~100-130us steady, cold 142us @ 1% util): R14 structure has
// 2 serial K-phases = 4 mid-kernel barriers + 2 serial 38KB stage stalls.
// R20 conv3f_k: stage ALL 8 c8 groups once (76KB tile, 4752 x 16B g2l16,
// one drain), 256 thr / 4 waves (wave = 1 out row, acc[2][8]=64 AGPR),
// 18 (s,tap) MFMA iters barrier-free. 78.6KB LDS -> 2 blocks/CU, 8 waves/CU
// (same as before, minus serialization). GAP epilogue keeps sGap combine.
// setup_k: prep+pack1+packT2+packT3+halo fused (5 dispatches -> 1).
// conv12/head unchanged (controls).
// ---------------------------------------------------------------------------

typedef __attribute__((ext_vector_type(8))) short short8;
typedef __attribute__((ext_vector_type(4))) float floatx4;
typedef __attribute__((ext_vector_type(4))) unsigned short ushort4v;
typedef __attribute__((ext_vector_type(4))) float float4v;

__device__ inline unsigned short f2bf(float f) {
  union { float f; unsigned u; } x;
  x.f = f;
  unsigned u = x.u;
  u += 0x7FFFu + ((u >> 16) & 1u);  // round-to-nearest-even
  return (unsigned short)(u >> 16);
}

// Async 16B global->LDS DMA. LDS dest = wave-uniform base + lane*16.
__device__ inline void g2l16(const unsigned short* g, unsigned short* l) {
  __builtin_amdgcn_global_load_lds(
      (const __attribute__((address_space(1))) unsigned int*)g,
      (__attribute__((address_space(3))) unsigned int*)(unsigned int)(uintptr_t)l,
      16, 0, 0);
}

// Fused setup: block 0 = prep (region decode + feat zero); remaining blocks
// cover pack1 | packT2 | packT3 | h2p halo as one linear index space.
//   pack1 : t in [0, 16384)
//   packT2: t in [16384, 163840)
//   packT3: t in [163840, 753664)
//   halo  : t in [753664, 753664 + nhalo)
__global__ __launch_bounds__(256) void setup_k(
    const int* __restrict__ rp, int* __restrict__ rout, float* __restrict__ feat,
    const float* __restrict__ w1, unsigned short* __restrict__ w1p,
    const float* __restrict__ w2, unsigned short* __restrict__ w2p,
    const float* __restrict__ w3, unsigned short* __restrict__ w3p,
    unsigned short* __restrict__ h2p, int nhalo) {
  const int tid = threadIdx.x;
  if (blockIdx.x == 0) {
    __shared__ int is64;
    if (tid == 0) {
      int odd_or = 0;
      for (int i = 0; i < 64; ++i) odd_or |= rp[2 * i + 1];
      is64 = (odd_or == 0) ? 1 : 0;
    }
    __syncthreads();
    if (tid < 128) {
      int r = is64 ? rp[2 * tid] : rp[tid];
      rout[tid] = r & 7;
      float* fr = feat + tid * 128;
      for (int j = 0; j < 128; ++j) fr[j] = 0.f;
    }
    return;
  }
  int t = (blockIdx.x - 1) * 256 + tid;
  if (t < 16384) {
    // conv1 weights -> [r][kg][mt][lane][j]
    int j = t & 7, lane = (t >> 3) & 63, mt = (t >> 9) & 1, kg = (t >> 10) & 1,
        r = t >> 11;
    int oc = mt * 16 + (lane & 15);
    int q = (lane >> 4) & 3;
    int row = kg * 2 + (q >> 1);
    int idx = (q & 1) * 8 + j;
    int kx = idx >> 2, c = idx & 3;
    float val = 0.f;
    if (row < 3 && kx < 3 && c < 3)
      val = w1[((r * 32 + oc) * 3 + c) * 9 + row * 3 + kx];
    w1p[t] = f2bf(val);
  } else if (t < 163840) {
    // conv2 weights: OC=64 IC=32 SUBK=1 MTG=4
    int t2 = t - 16384;
    int j = t2 & 7, lane = (t2 >> 3) & 63;
    int u = t2 >> 9;
    int mt = u & 3; u >>= 2;
    int tap = u % 9;
    int r = u / 9;
    int oc = mt * 16 + (lane & 15);
    int ic = ((lane >> 4) & 3) * 8 + j;
    w2p[t2] = f2bf(w2[((r * 64 + oc) * 32 + ic) * 9 + tap]);
  } else if (t < 753664) {
    // conv3 weights: OC=128 IC=64 SUBK=2 MTG=8
    int t3 = t - 163840;
    int j = t3 & 7, lane = (t3 >> 3) & 63;
    int u = t3 >> 9;
    int mt = u & 7; u >>= 3;
    int s = u & 1; u >>= 1;
    int tap = u % 9;
    int r = u / 9;
    int oc = mt * 16 + (lane & 15);
    int ic = s * 32 + ((lane >> 4) & 3) * 8 + j;
    w3p[t3] = f2bf(w3[((r * 128 + oc) * 64 + ic) * 9 + tap]);
  } else {
    // h2p halo zero: planes [C*8][66][66][8]
    int th = t - 753664;
    if (th < nhalo) {
      int s = th / 260, i = th - s * 260;
      int y, x;
      if (i < 66) { y = 0; x = i; }
      else if (i < 132) { y = 65; x = i - 66; }
      else {
        int ii = i - 132;
        y = 1 + (ii >> 1);
        x = (ii & 1) ? 65 : 0;
      }
      short8 z = {0, 0, 0, 0, 0, 0, 0, 0};
      *(short8*)(h2p + ((size_t)s * 66 * 66 + y * 66 + x) * 8) = z;
    }
  }
}

// FUSED conv1+conv2, two-phase img staging (R19b-verified). Block = conv2 out
// 4 rows x 32 px. Grid (xh 2, yg 16, sample C). 256 thr (wave = 1 out row).
__global__ __launch_bounds__(256, 3) void conv12_k(
    const float* __restrict__ img, const unsigned short* __restrict__ w1p,
    const float* __restrict__ b1, const unsigned short* __restrict__ w2p,
    const float* __restrict__ b2, const int* __restrict__ rgn,
    unsigned short* __restrict__ outp, int b0) {
  __shared__ unsigned short imgT[11 * 168 * 4];  // 14,784 B
  __shared__ unsigned short h1T[9 * 4 * 66 * 8]; // 38,016 B
  __shared__ float sB1[32];
  __shared__ float sB2[64];
  const int tid = threadIdx.x;
  const int xh = blockIdx.x;        // 0..1
  const int oy0 = blockIdx.y * 4;   // conv2 out row base 0..60
  const int bl = blockIdx.z;
  const int r = __builtin_amdgcn_readfirstlane(rgn[b0 + bl]);
  if (tid < 32) sB1[tid] = b1[r * 32 + tid];
  if (tid >= 64 && tid < 128) sB2[tid - 64] = b2[r * 64 + (tid - 64)];
  const float* ib = img + (size_t)(b0 + bl) * 3 * 65536;
  const int padx = xh ? 65 : 0;          // h1 zero-pad column in this tile
  const bool skiptop = (oy0 == 0);       // hy==0 is real h1 row -1
  const int rb = xh * 128 - 4;           // real img col of chunk elem 0

  const int n = tid & 15, q = (tid >> 4) & 3, wv = tid >> 6;
  const int lane = tid & 63;
  const short8* wpb1 = (const short8*)w1p + (size_t)r * 256 + lane;
  short8 afr1[2][2];
#pragma unroll
  for (int kg = 0; kg < 2; ++kg)
#pragma unroll
    for (int m = 0; m < 2; ++m) afr1[kg][m] = wpb1[(kg * 2 + m) * 64];

  auto STAGE = [&](int t0, int nrows) {
    const int nch = nrows * 41;
    for (int seg = 0; seg < nch; seg += 256) {
      int c = seg + tid;
      if (c < nch) {
        int i = c / 41, cq = c - i * 41;
        int rv = 4 * oy0 - 3 + t0 + i;     // real img row
        int cb = rb + 4 * cq;              // real img col of chunk elem 0
        unsigned short* dp = &imgT[((size_t)i * 168 + (4 * cq - 1)) * 4];
        if (rv >= 0 && cq > 0 && cb >= 0 && cb + 3 <= 255) {
          const float* p = ib + (size_t)rv * 256 + cb;
          float4v a = *(const float4v*)p;
          float4v bb = *(const float4v*)(p + 65536);
          float4v cc = *(const float4v*)(p + 131072);
#pragma unroll
          for (int e = 0; e < 4; ++e) {
            ushort4v v = {f2bf(a[e]), f2bf(bb[e]), f2bf(cc[e]), 0};
            *(ushort4v*)(dp + e * 4) = v;
          }
        } else {
          for (int e = (cq == 0 ? 1 : 0); e < 4; ++e) {
            int cc2 = cb + e;
            ushort4v v = {0, 0, 0, 0};
            if (rv >= 0 && cc2 >= 0 && cc2 <= 255) {
              const float* p = ib + (size_t)rv * 256 + cc2;
              v.x = f2bf(p[0]);
              v.y = f2bf(p[65536]);
              v.z = f2bf(p[131072]);
            }
            *(ushort4v*)(dp + e * 4) = v;
          }
        }
      }
    }
  };

  auto CONV1ROW = [&](int hy, int phaseB) {
    floatx4 a1[5][2];
#pragma unroll
    for (int nt = 0; nt < 5; ++nt)
#pragma unroll
      for (int m = 0; m < 2; ++m) a1[nt][m] = (floatx4){0.f, 0.f, 0.f, 0.f};
#pragma unroll
    for (int kg = 0; kg < 2; ++kg) {
      int row = kg * 2 + (q >> 1);
      int rowc = (row < 3) ? row : 0;  // pad row: zero weights, safe addr
      int tr = 2 * hy + rowc;
      int slot = phaseB ? (tr >= 11 ? tr - 11 : tr) : tr;
#pragma unroll
      for (int nt = 0; nt < 5; ++nt) {
        int lx = nt * 16 + n;          // h1 local px 0..79 (use 0..65)
        short8 bfr = *(const short8*)&imgT[((size_t)slot * 168 + 2 * lx) * 4 +
                                           (q & 1) * 8];
#pragma unroll
        for (int m = 0; m < 2; ++m)
          a1[nt][m] = __builtin_amdgcn_mfma_f32_16x16x32_bf16(
              afr1[kg][m], bfr, a1[nt][m], 0, 0, 0);
      }
    }
#pragma unroll
    for (int nt = 0; nt < 5; ++nt) {
      int lx = nt * 16 + n;
      bool ok = (lx <= 65) && (lx != padx) && !(skiptop && hy == 0);
      if (ok) {
#pragma unroll
        for (int m = 0; m < 2; ++m) {
          ushort4v st;
#pragma unroll
          for (int rr = 0; rr < 4; ++rr) {
            float v = a1[nt][m][rr] + sB1[m * 16 + q * 4 + rr];
            st[rr] = f2bf(v > 0.f ? v : 0.f);
          }
          int cg = m * 2 + (q >> 1);
          *(ushort4v*)&h1T[(((size_t)hy * 4 + cg) * 66 + lx) * 8 +
                           (q & 1) * 4] = st;
        }
      }
    }
  };

  // ---- phase A: stage rows 0..10 + zero h1 pad cells
  STAGE(0, 11);
  {
    short8 z8 = {0, 0, 0, 0, 0, 0, 0, 0};
    if (tid < 36) {  // pad column, all 9 hy x 4 cg
      int hy = tid / 4, cg = tid % 4;
      *(short8*)&h1T[(((size_t)hy * 4 + cg) * 66 + padx) * 8] = z8;
    }
    if (skiptop) {  // hy==0 row (real h1 row -1)
      for (int c = tid; c < 264; c += 256) {  // 4 cg x 66 x
        int cg = c / 66, x = c - cg * 66;
        *(short8*)&h1T[(((size_t)0 * 4 + cg) * 66 + x) * 8] = z8;
      }
    }
  }
  __syncthreads();

  // ---- conv1 A: hy 0..4 (wave wv does hy = wv, wv+4 if <=4)
  for (int hy = wv; hy <= 4; hy += 4) CONV1ROW(hy, 0);
  __syncthreads();  // conv1-A img reads done before restage

  // ---- phase B: stage rows 11..18 into slots 0..7 (slot 10 = row 10 kept)
  STAGE(11, 8);
  __syncthreads();

  // ---- conv1 B: hy 5..8
  CONV1ROW(5 + wv, 1);
  __syncthreads();

  // ---- conv2: out 4 rows x 32 px, 64 oc
  const short8* wpb2 = (const short8*)w2p + (size_t)r * 9 * 4 * 64 + lane;
  floatx4 a2[2][4];
#pragma unroll
  for (int nt = 0; nt < 2; ++nt)
#pragma unroll
    for (int m = 0; m < 4; ++m) a2[nt][m] = (floatx4){0.f, 0.f, 0.f, 0.f};
#pragma unroll
  for (int tap = 0; tap < 9; ++tap) {
    const int ky = tap / 3, kx = tap % 3;
    short8 af[4];
#pragma unroll
    for (int m = 0; m < 4; ++m) af[m] = wpb2[(tap * 4 + m) * 64];
    short8 bf[2];
#pragma unroll
    for (int nt = 0; nt < 2; ++nt) {
      int ox = nt * 16 + n;  // local out px 0..31
      bf[nt] = *(const short8*)&h1T[((((2 * wv + ky) << 2) + q) * 66 +
                                    (2 * ox + kx)) * 8];
    }
#pragma unroll
    for (int m = 0; m < 4; ++m)
#pragma unroll
      for (int nt = 0; nt < 2; ++nt)
        a2[nt][m] = __builtin_amdgcn_mfma_f32_16x16x32_bf16(af[m], bf[nt],
                                                            a2[nt][m], 0, 0, 0);
  }
  unsigned short* ob = outp + (size_t)bl * 8 * 66 * 66 * 8;
  const int oy = oy0 + wv;
#pragma unroll
  for (int nt = 0; nt < 2; ++nt) {
    int ox = xh * 32 + nt * 16 + n;
#pragma unroll
    for (int m = 0; m < 4; ++m) {
      ushort4v st;
#pragma unroll
      for (int rr = 0; rr < 4; ++rr) {
        float v = a2[nt][m][rr] + sB2[m * 16 + q * 4 + rr];
        st[rr] = f2bf(v > 0.f ? v : 0.f);
      }
      int cg = m * 2 + (q >> 1);  // oc/8
      *(ushort4v*)&ob[(((size_t)cg * 66 + oy + 1) * 66 + ox + 1) * 8 +
                      (q & 1) * 4] = st;
    }
  }
}

// conv3 SINGLE-STAGE: 64->128, fused bias+ReLU+GAP. h2p [c8=8][66][66][8].
// Block = 256 thr (4 waves; wave = 1 out row x 32 px, all 128 oc, acc[2][8]).
// Full-K tile [iy 9][c8 8][x 66][8] = 76,032 B staged ONCE (4752 x 16B
// g2l16, single drain), then 18 (s,tap) MFMA iterations barrier-free.
__global__ __launch_bounds__(256, 2) void conv3f_k(
    const unsigned short* __restrict__ in, const unsigned short* __restrict__ wp,
    const float* __restrict__ bias, const int* __restrict__ rgn,
    float* __restrict__ feat, int b0) {
  __shared__ unsigned short tile[9 * 8 * 66 * 8];  // 76,032 B
  __shared__ float sBias[128];
  __shared__ float sGap[4 * 128];
  const int tid = threadIdx.x;
  const int bl = blockIdx.y;
  const int b = b0 + bl;
  const int r = __builtin_amdgcn_readfirstlane(rgn[b]);
  if (tid < 128) sBias[tid] = bias[r * 128 + tid];
  const int oy0 = blockIdx.x * 4;
  const unsigned short* gbase = in + (size_t)bl * 8 * 66 * 66 * 8;
  const int lane = tid & 63, wv = tid >> 6;
  const int n = lane & 15, q = (lane >> 4) & 3;

  // stage full K tile: chunk c = (iy*8 + c8)*66 + x  ->  LDS offset c*16B
  for (int seg = 0; seg < 4752; seg += 256) {
    int c = seg + tid;
    if (c < 4752) {
      int iy = c / 528;           // 8*66 chunks per input row
      int rem = c - iy * 528;
      int c8 = rem / 66;
      int x = rem - c8 * 66;
      const unsigned short* gp =
          gbase + (((size_t)c8 * 66 + 2 * oy0 + iy) * 66 + x) * 8;
      g2l16(gp, tile + (size_t)(seg + wv * 64) * 8);
    }
  }
  __syncthreads();

  const short8* wpb = (const short8*)wp + (size_t)r * 9 * 2 * 8 * 64 + lane;
  floatx4 acc[2][8];
#pragma unroll
  for (int nt = 0; nt < 2; ++nt)
#pragma unroll
    for (int m = 0; m < 8; ++m) acc[nt][m] = (floatx4){0.f, 0.f, 0.f, 0.f};

#pragma unroll
  for (int s = 0; s < 2; ++s)
#pragma unroll
    for (int tap = 0; tap < 9; ++tap) {
      const int ky = tap / 3, kx = tap % 3;
      short8 afr[8];
#pragma unroll
      for (int m = 0; m < 8; ++m) afr[m] = wpb[((tap * 2 + s) * 8 + m) * 64];
      short8 bfr[2];
#pragma unroll
      for (int nt = 0; nt < 2; ++nt) {
        int ox = nt * 16 + n;  // 0..31
        bfr[nt] = *(const short8*)&tile[((((2 * wv + ky) * 8) + s * 4 + q) * 66 +
                                        (2 * ox + kx)) * 8];
      }
#pragma unroll
      for (int m = 0; m < 8; ++m)
#pragma unroll
        for (int nt = 0; nt < 2; ++nt)
          acc[nt][m] = __builtin_amdgcn_mfma_f32_16x16x32_bf16(afr[m], bfr[nt],
                                                               acc[nt][m], 0, 0, 0);
    }

  // bias + ReLU + GAP: shfl reduce over 16 px lanes, LDS cross-wave combine
#pragma unroll
  for (int m = 0; m < 8; ++m)
#pragma unroll
    for (int rr = 0; rr < 4; ++rr) {
      float bv = sBias[m * 16 + q * 4 + rr];
      float vs = 0.f;
#pragma unroll
      for (int nt = 0; nt < 2; ++nt) {
        float v = acc[nt][m][rr] + bv;
        vs += (v > 0.f ? v : 0.f);
      }
      vs += __shfl_xor(vs, 1, 16);
      vs += __shfl_xor(vs, 2, 16);
      vs += __shfl_xor(vs, 4, 16);
      vs += __shfl_xor(vs, 8, 16);
      if (n == 0) sGap[wv * 128 + m * 16 + q * 4 + rr] = vs;
    }
  __syncthreads();
  if (tid < 128)
    atomicAdd(&feat[b * 128 + tid],
              sGap[tid] + sGap[128 + tid] + sGap[256 + tid] + sGap[384 + tid]);
}

__global__ __launch_bounds__(256) void head_k(
    const float* __restrict__ feat, const float* __restrict__ fw,
    const float* __restrict__ fb, const int* __restrict__ rgn,
    float* __restrict__ out) {
  int t = threadIdx.x;  // 128 samples x 2 classes
  int b = t >> 1, c = t & 1;
  int r = rgn[b];
  const float* fwr = fw + (r * 2 + c) * 128;
  const float* fv = feat + b * 128;
  float a = 0.f;
#pragma unroll 8
  for (int j = 0; j < 128; ++j) a = fmaf(fwr[j], fv[j], a);
  out[t] = a * (1.0f / 1024.0f) + fb[r * 2 + c];
}

extern "C" void kernel_launch(void* const* d_in, const int* in_sizes, int n_in,
                              void* d_out, int out_size, void* d_ws, size_t ws_size,
                              hipStream_t stream) {
  const float* img = (const float*)d_in[0];
  const int* rgn_raw = (const int*)d_in[1];
  const float* w1 = (const float*)d_in[2];
  const float* b1 = (const float*)d_in[3];
  const float* w2 = (const float*)d_in[4];
  const float* b2 = (const float*)d_in[5];
  const float* w3 = (const float*)d_in[6];
  const float* b3 = (const float*)d_in[7];
  const float* fw = (const float*)d_in[8];
  const float* fb = (const float*)d_in[9];
  float* out = (float*)d_out;

  const size_t h2p_s = (size_t)8 * 66 * 66 * 8 * 2;  // 557 KB
  const size_t per_sample = h2p_s;
  const size_t fixed = (size_t)16384 * 2 + (size_t)147456 * 2 +
                       (size_t)589824 * 2 + 128 * 128 * 4 + 512 + 16 * 256;
  int C = 128;
  while (C > 1 && fixed + (size_t)C * per_sample > ws_size) C >>= 1;

  char* ws = (char*)d_ws;
  size_t off = 0;
  auto alloc = [&](size_t bytes) {
    char* p = ws + off;
    off += (bytes + 255) & ~(size_t)255;
    return p;
  };
  unsigned short* h2p = (unsigned short*)alloc((size_t)C * h2p_s);
  unsigned short* w1p = (unsigned short*)alloc((size_t)16384 * 2);
  unsigned short* w2p = (unsigned short*)alloc((size_t)147456 * 2);
  unsigned short* w3p = (unsigned short*)alloc((size_t)589824 * 2);
  float* feat = (float*)alloc((size_t)128 * 128 * 4);
  int* rgn = (int*)alloc((size_t)128 * 4);

  // fused setup: prep + pack1 + packT2 + packT3 + h2p halo
  {
    int nhalo = C * 8 * 260;
    int total = 753664 + nhalo;
    int nblk = 1 + (total + 255) / 256;
    hipLaunchKernelGGL(setup_k, dim3(nblk), dim3(256), 0, stream,
                       rgn_raw, rgn, feat, w1, w1p, w2, w2p, w3, w3p, h2p, nhalo);
  }

  for (int b0 = 0; b0 < 128; b0 += C) {
    // fused conv1+conv2: grid (x-half, 16 row-groups, sample)
    hipLaunchKernelGGL(conv12_k, dim3(2, 16, C), dim3(256), 0, stream,
                       img, w1p, b1, w2p, b2, rgn, h2p, b0);
    // conv3 single-stage: 8 row-group blocks per sample, 256 thr
    hipLaunchKernelGGL(conv3f_k, dim3(8, C), dim3(256), 0, stream,
                       h2p, w3p, b3, rgn, feat, b0);
  }
  hipLaunchKernelGGL(head_k, dim3(1), dim3(256), 0, stream, feat, fw, fb, rgn, out);
}

// Round 9
// 293.105 us; speedup vs baseline: 1.0253x; 1.0253x over previous
//
#include <hip/hip_runtime.h>
#include <cstdint>

// ---------------------------------------------------------------------------
// RegionModel R21: T14 issue-early/use-late staging in conv12 + conv3.
// R20 lessons: conv3 single-stage = neutral (staging still fully serial);
// conv12 108->120 on identical code = session variance. conv3's cost is
// un-overlapped staging, not barrier count.
// R21:
//  - conv3d_k: 2 half-tiles (38KB each). stage(h0); bar; ISSUE stage(h1)
//    (g2l16 fire-and-forget, ~10 vmem/wave); compute(s0); bar (drains h1);
//    compute(s1). Half the stage latency hides under compute; loads never
//    cross a barrier before their drain point (R17's failure mode avoided).
//  - conv12_k: phase-B stage split: LOADB (fast chunks -> 24 VGPR) issued
//    after the phase-A barrier; conv1-A computes; bar drains; STOREB
//    converts+writes LDS (slow edge chunks inline). T14, +17% precedent.
// setup_k/head unchanged.
// ---------------------------------------------------------------------------

typedef __attribute__((ext_vector_type(8))) short short8;
typedef __attribute__((ext_vector_type(4))) float floatx4;
typedef __attribute__((ext_vector_type(4))) unsigned short ushort4v;
typedef __attribute__((ext_vector_type(4))) float float4v;

__device__ inline unsigned short f2bf(float f) {
  union { float f; unsigned u; } x;
  x.f = f;
  unsigned u = x.u;
  u += 0x7FFFu + ((u >> 16) & 1u);  // round-to-nearest-even
  return (unsigned short)(u >> 16);
}

// Async 16B global->LDS DMA. LDS dest = wave-uniform base + lane*16.
__device__ inline void g2l16(const unsigned short* g, unsigned short* l) {
  __builtin_amdgcn_global_load_lds(
      (const __attribute__((address_space(1))) unsigned int*)g,
      (__attribute__((address_space(3))) unsigned int*)(unsigned int)(uintptr_t)l,
      16, 0, 0);
}

// Fused setup: block 0 = prep (region decode + feat zero); remaining blocks
// cover pack1 | packT2 | packT3 | h2p halo as one linear index space.
__global__ __launch_bounds__(256) void setup_k(
    const int* __restrict__ rp, int* __restrict__ rout, float* __restrict__ feat,
    const float* __restrict__ w1, unsigned short* __restrict__ w1p,
    const float* __restrict__ w2, unsigned short* __restrict__ w2p,
    const float* __restrict__ w3, unsigned short* __restrict__ w3p,
    unsigned short* __restrict__ h2p, int nhalo) {
  const int tid = threadIdx.x;
  if (blockIdx.x == 0) {
    __shared__ int is64;
    if (tid == 0) {
      int odd_or = 0;
      for (int i = 0; i < 64; ++i) odd_or |= rp[2 * i + 1];
      is64 = (odd_or == 0) ? 1 : 0;
    }
    __syncthreads();
    if (tid < 128) {
      int r = is64 ? rp[2 * tid] : rp[tid];
      rout[tid] = r & 7;
      float* fr = feat + tid * 128;
      for (int j = 0; j < 128; ++j) fr[j] = 0.f;
    }
    return;
  }
  int t = (blockIdx.x - 1) * 256 + tid;
  if (t < 16384) {
    int j = t & 7, lane = (t >> 3) & 63, mt = (t >> 9) & 1, kg = (t >> 10) & 1,
        r = t >> 11;
    int oc = mt * 16 + (lane & 15);
    int q = (lane >> 4) & 3;
    int row = kg * 2 + (q >> 1);
    int idx = (q & 1) * 8 + j;
    int kx = idx >> 2, c = idx & 3;
    float val = 0.f;
    if (row < 3 && kx < 3 && c < 3)
      val = w1[((r * 32 + oc) * 3 + c) * 9 + row * 3 + kx];
    w1p[t] = f2bf(val);
  } else if (t < 163840) {
    int t2 = t - 16384;
    int j = t2 & 7, lane = (t2 >> 3) & 63;
    int u = t2 >> 9;
    int mt = u & 3; u >>= 2;
    int tap = u % 9;
    int r = u / 9;
    int oc = mt * 16 + (lane & 15);
    int ic = ((lane >> 4) & 3) * 8 + j;
    w2p[t2] = f2bf(w2[((r * 64 + oc) * 32 + ic) * 9 + tap]);
  } else if (t < 753664) {
    int t3 = t - 163840;
    int j = t3 & 7, lane = (t3 >> 3) & 63;
    int u = t3 >> 9;
    int mt = u & 7; u >>= 3;
    int s = u & 1; u >>= 1;
    int tap = u % 9;
    int r = u / 9;
    int oc = mt * 16 + (lane & 15);
    int ic = s * 32 + ((lane >> 4) & 3) * 8 + j;
    w3p[t3] = f2bf(w3[((r * 128 + oc) * 64 + ic) * 9 + tap]);
  } else {
    int th = t - 753664;
    if (th < nhalo) {
      int s = th / 260, i = th - s * 260;
      int y, x;
      if (i < 66) { y = 0; x = i; }
      else if (i < 132) { y = 65; x = i - 66; }
      else {
        int ii = i - 132;
        y = 1 + (ii >> 1);
        x = (ii & 1) ? 65 : 0;
      }
      short8 z = {0, 0, 0, 0, 0, 0, 0, 0};
      *(short8*)(h2p + ((size_t)s * 66 * 66 + y * 66 + x) * 8) = z;
    }
  }
}

// FUSED conv1+conv2, two-phase img staging; phase-B via T14 reg-prefetch.
// Block = conv2 out 4 rows x 32 px. Grid (xh 2, yg 16, sample C). 256 thr.
__global__ __launch_bounds__(256, 3) void conv12_k(
    const float* __restrict__ img, const unsigned short* __restrict__ w1p,
    const float* __restrict__ b1, const unsigned short* __restrict__ w2p,
    const float* __restrict__ b2, const int* __restrict__ rgn,
    unsigned short* __restrict__ outp, int b0) {
  __shared__ unsigned short imgT[11 * 168 * 4];  // 14,784 B
  __shared__ unsigned short h1T[9 * 4 * 66 * 8]; // 38,016 B
  __shared__ float sB1[32];
  __shared__ float sB2[64];
  const int tid = threadIdx.x;
  const int xh = blockIdx.x;        // 0..1
  const int oy0 = blockIdx.y * 4;   // conv2 out row base 0..60
  const int bl = blockIdx.z;
  const int r = __builtin_amdgcn_readfirstlane(rgn[b0 + bl]);
  if (tid < 32) sB1[tid] = b1[r * 32 + tid];
  if (tid >= 64 && tid < 128) sB2[tid - 64] = b2[r * 64 + (tid - 64)];
  const float* ib = img + (size_t)(b0 + bl) * 3 * 65536;
  const int padx = xh ? 65 : 0;          // h1 zero-pad column in this tile
  const bool skiptop = (oy0 == 0);       // hy==0 is real h1 row -1
  const int rb = xh * 128 - 4;           // real img col of chunk elem 0

  const int n = tid & 15, q = (tid >> 4) & 3, wv = tid >> 6;
  const int lane = tid & 63;
  const short8* wpb1 = (const short8*)w1p + (size_t)r * 256 + lane;
  short8 afr1[2][2];
#pragma unroll
  for (int kg = 0; kg < 2; ++kg)
#pragma unroll
    for (int m = 0; m < 2; ++m) afr1[kg][m] = wpb1[(kg * 2 + m) * 64];

  // phase-A staging (R19b-verified form): rows 0..10 -> slots 0..10
  {
    const int nch = 11 * 41;  // 451
    for (int seg = 0; seg < nch; seg += 256) {
      int c = seg + tid;
      if (c < nch) {
        int i = c / 41, cq = c - i * 41;
        int rv = 4 * oy0 - 3 + i;          // real img row
        int cb = rb + 4 * cq;              // real img col of chunk elem 0
        unsigned short* dp = &imgT[((size_t)i * 168 + (4 * cq - 1)) * 4];
        if (rv >= 0 && cq > 0 && cb >= 0 && cb + 3 <= 255) {
          const float* p = ib + (size_t)rv * 256 + cb;
          float4v a = *(const float4v*)p;
          float4v bb = *(const float4v*)(p + 65536);
          float4v cc = *(const float4v*)(p + 131072);
#pragma unroll
          for (int e = 0; e < 4; ++e) {
            ushort4v v = {f2bf(a[e]), f2bf(bb[e]), f2bf(cc[e]), 0};
            *(ushort4v*)(dp + e * 4) = v;
          }
        } else {
          for (int e = (cq == 0 ? 1 : 0); e < 4; ++e) {
            int cc2 = cb + e;
            ushort4v v = {0, 0, 0, 0};
            if (rv >= 0 && cc2 >= 0 && cc2 <= 255) {
              const float* p = ib + (size_t)rv * 256 + cc2;
              v.x = f2bf(p[0]);
              v.y = f2bf(p[65536]);
              v.z = f2bf(p[131072]);
            }
            *(ushort4v*)(dp + e * 4) = v;
          }
        }
      }
    }
  }
  // zero h1 pad cells
  {
    short8 z8 = {0, 0, 0, 0, 0, 0, 0, 0};
    if (tid < 36) {  // pad column, all 9 hy x 4 cg
      int hy = tid / 4, cg = tid % 4;
      *(short8*)&h1T[(((size_t)hy * 4 + cg) * 66 + padx) * 8] = z8;
    }
    if (skiptop) {  // hy==0 row (real h1 row -1)
      for (int c = tid; c < 264; c += 256) {
        int cg = c / 66, x = c - cg * 66;
        *(short8*)&h1T[(((size_t)0 * 4 + cg) * 66 + x) * 8] = z8;
      }
    }
  }

  auto CONV1ROW = [&](int hy, int phaseB) {
    floatx4 a1[5][2];
#pragma unroll
    for (int nt = 0; nt < 5; ++nt)
#pragma unroll
      for (int m = 0; m < 2; ++m) a1[nt][m] = (floatx4){0.f, 0.f, 0.f, 0.f};
#pragma unroll
    for (int kg = 0; kg < 2; ++kg) {
      int row = kg * 2 + (q >> 1);
      int rowc = (row < 3) ? row : 0;  // pad row: zero weights, safe addr
      int tr = 2 * hy + rowc;
      int slot = phaseB ? (tr >= 11 ? tr - 11 : tr) : tr;
#pragma unroll
      for (int nt = 0; nt < 5; ++nt) {
        int lx = nt * 16 + n;          // h1 local px 0..79 (use 0..65)
        short8 bfr = *(const short8*)&imgT[((size_t)slot * 168 + 2 * lx) * 4 +
                                           (q & 1) * 8];
#pragma unroll
        for (int m = 0; m < 2; ++m)
          a1[nt][m] = __builtin_amdgcn_mfma_f32_16x16x32_bf16(
              afr1[kg][m], bfr, a1[nt][m], 0, 0, 0);
      }
    }
#pragma unroll
    for (int nt = 0; nt < 5; ++nt) {
      int lx = nt * 16 + n;
      bool ok = (lx <= 65) && (lx != padx) && !(skiptop && hy == 0);
      if (ok) {
#pragma unroll
        for (int m = 0; m < 2; ++m) {
          ushort4v st;
#pragma unroll
          for (int rr = 0; rr < 4; ++rr) {
            float v = a1[nt][m][rr] + sB1[m * 16 + q * 4 + rr];
            st[rr] = f2bf(v > 0.f ? v : 0.f);
          }
          int cg = m * 2 + (q >> 1);
          *(ushort4v*)&h1T[(((size_t)hy * 4 + cg) * 66 + lx) * 8 +
                           (q & 1) * 4] = st;
        }
      }
    }
  };

  __syncthreads();  // phase-A tile + pads ready

  // ---- T14: issue phase-B fast-path loads NOW (rows 11..18, rv always valid)
  // 328 chunks; thread covers c = tid and c = tid+256 (tid<72).
  float4v Lb0[3], Lb1[3];
  int ok0 = 0, ok1 = 0;
  {
    int c = tid;  // < 328 always
    int i = c / 41, cq = c - i * 41;
    int cb = rb + 4 * cq;
    if (cq > 0 && cb >= 0 && cb + 3 <= 255) {
      const float* p = ib + (size_t)(4 * oy0 + 8 + i) * 256 + cb;
      Lb0[0] = *(const float4v*)p;
      Lb0[1] = *(const float4v*)(p + 65536);
      Lb0[2] = *(const float4v*)(p + 131072);
      ok0 = 1;
    }
    c = tid + 256;
    if (c < 328) {
      i = c / 41; cq = c - i * 41; cb = rb + 4 * cq;
      if (cq > 0 && cb >= 0 && cb + 3 <= 255) {
        const float* p = ib + (size_t)(4 * oy0 + 8 + i) * 256 + cb;
        Lb1[0] = *(const float4v*)p;
        Lb1[1] = *(const float4v*)(p + 65536);
        Lb1[2] = *(const float4v*)(p + 131072);
        ok1 = 1;
      }
    }
  }

  // ---- conv1 A: hy 0..4 (loads above land during this compute)
  for (int hy = wv; hy <= 4; hy += 4) CONV1ROW(hy, 0);
  __syncthreads();  // conv1-A img reads done; Lb loads drained

  // ---- STOREB: convert regs -> slots 0..7 (slow edge chunks inline)
  auto STOREB = [&](int c, const float4v* L, int okf) {
    int i = c / 41, cq = c - i * 41;
    int cb = rb + 4 * cq;
    unsigned short* dp = &imgT[((size_t)i * 168 + (4 * cq - 1)) * 4];
    if (okf) {
#pragma unroll
      for (int e = 0; e < 4; ++e) {
        ushort4v v = {f2bf(L[0][e]), f2bf(L[1][e]), f2bf(L[2][e]), 0};
        *(ushort4v*)(dp + e * 4) = v;
      }
    } else {
      int rv = 4 * oy0 + 8 + i;
      for (int e = (cq == 0 ? 1 : 0); e < 4; ++e) {
        int cc2 = cb + e;
        ushort4v v = {0, 0, 0, 0};
        if (cc2 >= 0 && cc2 <= 255) {
          const float* p = ib + (size_t)rv * 256 + cc2;
          v.x = f2bf(p[0]);
          v.y = f2bf(p[65536]);
          v.z = f2bf(p[131072]);
        }
        *(ushort4v*)(dp + e * 4) = v;
      }
    }
  };
  STOREB(tid, Lb0, ok0);
  if (tid + 256 < 328) STOREB(tid + 256, Lb1, ok1);
  __syncthreads();

  // ---- conv1 B: hy 5..8
  CONV1ROW(5 + wv, 1);
  __syncthreads();

  // ---- conv2: out 4 rows x 32 px, 64 oc
  const short8* wpb2 = (const short8*)w2p + (size_t)r * 9 * 4 * 64 + lane;
  floatx4 a2[2][4];
#pragma unroll
  for (int nt = 0; nt < 2; ++nt)
#pragma unroll
    for (int m = 0; m < 4; ++m) a2[nt][m] = (floatx4){0.f, 0.f, 0.f, 0.f};
#pragma unroll
  for (int tap = 0; tap < 9; ++tap) {
    const int ky = tap / 3, kx = tap % 3;
    short8 af[4];
#pragma unroll
    for (int m = 0; m < 4; ++m) af[m] = wpb2[(tap * 4 + m) * 64];
    short8 bf[2];
#pragma unroll
    for (int nt = 0; nt < 2; ++nt) {
      int ox = nt * 16 + n;  // local out px 0..31
      bf[nt] = *(const short8*)&h1T[((((2 * wv + ky) << 2) + q) * 66 +
                                    (2 * ox + kx)) * 8];
    }
#pragma unroll
    for (int m = 0; m < 4; ++m)
#pragma unroll
      for (int nt = 0; nt < 2; ++nt)
        a2[nt][m] = __builtin_amdgcn_mfma_f32_16x16x32_bf16(af[m], bf[nt],
                                                            a2[nt][m], 0, 0, 0);
  }
  unsigned short* ob = outp + (size_t)bl * 8 * 66 * 66 * 8;
  const int oy = oy0 + wv;
#pragma unroll
  for (int nt = 0; nt < 2; ++nt) {
    int ox = xh * 32 + nt * 16 + n;
#pragma unroll
    for (int m = 0; m < 4; ++m) {
      ushort4v st;
#pragma unroll
      for (int rr = 0; rr < 4; ++rr) {
        float v = a2[nt][m][rr] + sB2[m * 16 + q * 4 + rr];
        st[rr] = f2bf(v > 0.f ? v : 0.f);
      }
      int cg = m * 2 + (q >> 1);  // oc/8
      *(ushort4v*)&ob[(((size_t)cg * 66 + oy + 1) * 66 + ox + 1) * 8 +
                      (q & 1) * 4] = st;
    }
  }
}

// conv3 DOUBLE-BUFFERED: 64->128, fused bias+ReLU+GAP. h2p [c8=8][66][66][8].
// Block = 256 thr (4 waves; wave = 1 out row x 32 px, all 128 oc).
// Half-tile [iy 9][c8' 4][x 66][8] = 38,016 B per K-half.
// stage(h0); bar; ISSUE stage(h1); compute(s0); bar(drain); compute(s1).
__global__ __launch_bounds__(256, 2) void conv3d_k(
    const unsigned short* __restrict__ in, const unsigned short* __restrict__ wp,
    const float* __restrict__ bias, const int* __restrict__ rgn,
    float* __restrict__ feat, int b0) {
  __shared__ unsigned short tile[2][9 * 4 * 66 * 8];  // 2 x 38,016 B
  __shared__ float sBias[128];
  __shared__ float sGap[4 * 128];
  const int tid = threadIdx.x;
  const int bl = blockIdx.y;
  const int b = b0 + bl;
  const int r = __builtin_amdgcn_readfirstlane(rgn[b]);
  if (tid < 128) sBias[tid] = bias[r * 128 + tid];
  const int oy0 = blockIdx.x * 4;
  const unsigned short* gbase = in + (size_t)bl * 8 * 66 * 66 * 8;
  const int lane = tid & 63, wv = tid >> 6;
  const int n = lane & 15, q = (lane >> 4) & 3;

  auto STG = [&](int s) {
    for (int seg = 0; seg < 2376; seg += 256) {
      int c = seg + tid;
      if (c < 2376) {
        int iy = c / 264;
        int rem = c - iy * 264;
        int c8 = rem / 66;
        int x = rem - c8 * 66;
        const unsigned short* gp =
            gbase + (((size_t)(s * 4 + c8) * 66 + 2 * oy0 + iy) * 66 + x) * 8;
        g2l16(gp, tile[s] + (size_t)(seg + wv * 64) * 8);
      }
    }
  };

  const short8* wpb = (const short8*)wp + (size_t)r * 9 * 2 * 8 * 64 + lane;
  floatx4 acc[2][8];
#pragma unroll
  for (int nt = 0; nt < 2; ++nt)
#pragma unroll
    for (int m = 0; m < 8; ++m) acc[nt][m] = (floatx4){0.f, 0.f, 0.f, 0.f};

  auto COMPUTE = [&](int s) {
#pragma unroll
    for (int tap = 0; tap < 9; ++tap) {
      const int ky = tap / 3, kx = tap % 3;
      short8 afr[8];
#pragma unroll
      for (int m = 0; m < 8; ++m) afr[m] = wpb[((tap * 2 + s) * 8 + m) * 64];
      short8 bfr[2];
#pragma unroll
      for (int nt = 0; nt < 2; ++nt) {
        int ox = nt * 16 + n;  // 0..31
        bfr[nt] = *(const short8*)&tile[s][(((2 * wv + ky) * 4 + q) * 66 +
                                          (2 * ox + kx)) * 8];
      }
#pragma unroll
      for (int m = 0; m < 8; ++m)
#pragma unroll
        for (int nt = 0; nt < 2; ++nt)
          acc[nt][m] = __builtin_amdgcn_mfma_f32_16x16x32_bf16(afr[m], bfr[nt],
                                                               acc[nt][m], 0, 0, 0);
    }
  };

  STG(0);
  __syncthreads();   // half-0 ready
  STG(1);            // fire-and-forget; drains at the next barrier
  COMPUTE(0);        // hides half-1 stage latency
  __syncthreads();   // half-1 ready
  COMPUTE(1);

  // bias + ReLU + GAP: shfl reduce over 16 px lanes, LDS cross-wave combine
#pragma unroll
  for (int m = 0; m < 8; ++m)
#pragma unroll
    for (int rr = 0; rr < 4; ++rr) {
      float bv = sBias[m * 16 + q * 4 + rr];
      float vs = 0.f;
#pragma unroll
      for (int nt = 0; nt < 2; ++nt) {
        float v = acc[nt][m][rr] + bv;
        vs += (v > 0.f ? v : 0.f);
      }
      vs += __shfl_xor(vs, 1, 16);
      vs += __shfl_xor(vs, 2, 16);
      vs += __shfl_xor(vs, 4, 16);
      vs += __shfl_xor(vs, 8, 16);
      if (n == 0) sGap[wv * 128 + m * 16 + q * 4 + rr] = vs;
    }
  __syncthreads();
  if (tid < 128)
    atomicAdd(&feat[b * 128 + tid],
              sGap[tid] + sGap[128 + tid] + sGap[256 + tid] + sGap[384 + tid]);
}

__global__ __launch_bounds__(256) void head_k(
    const float* __restrict__ feat, const float* __restrict__ fw,
    const float* __restrict__ fb, const int* __restrict__ rgn,
    float* __restrict__ out) {
  int t = threadIdx.x;  // 128 samples x 2 classes
  int b = t >> 1, c = t & 1;
  int r = rgn[b];
  const float* fwr = fw + (r * 2 + c) * 128;
  const float* fv = feat + b * 128;
  float a = 0.f;
#pragma unroll 8
  for (int j = 0; j < 128; ++j) a = fmaf(fwr[j], fv[j], a);
  out[t] = a * (1.0f / 1024.0f) + fb[r * 2 + c];
}

extern "C" void kernel_launch(void* const* d_in, const int* in_sizes, int n_in,
                              void* d_out, int out_size, void* d_ws, size_t ws_size,
                              hipStream_t stream) {
  const float* img = (const float*)d_in[0];
  const int* rgn_raw = (const int*)d_in[1];
  const float* w1 = (const float*)d_in[2];
  const float* b1 = (const float*)d_in[3];
  const float* w2 = (const float*)d_in[4];
  const float* b2 = (const float*)d_in[5];
  const float* w3 = (const float*)d_in[6];
  const float* b3 = (const float*)d_in[7];
  const float* fw = (const float*)d_in[8];
  const float* fb = (const float*)d_in[9];
  float* out = (float*)d_out;

  const size_t h2p_s = (size_t)8 * 66 * 66 * 8 * 2;  // 557 KB
  const size_t per_sample = h2p_s;
  const size_t fixed = (size_t)16384 * 2 + (size_t)147456 * 2 +
                       (size_t)589824 * 2 + 128 * 128 * 4 + 512 + 16 * 256;
  int C = 128;
  while (C > 1 && fixed + (size_t)C * per_sample > ws_size) C >>= 1;

  char* ws = (char*)d_ws;
  size_t off = 0;
  auto alloc = [&](size_t bytes) {
    char* p = ws + off;
    off += (bytes + 255) & ~(size_t)255;
    return p;
  };
  unsigned short* h2p = (unsigned short*)alloc((size_t)C * h2p_s);
  unsigned short* w1p = (unsigned short*)alloc((size_t)16384 * 2);
  unsigned short* w2p = (unsigned short*)alloc((size_t)147456 * 2);
  unsigned short* w3p = (unsigned short*)alloc((size_t)589824 * 2);
  float* feat = (float*)alloc((size_t)128 * 128 * 4);
  int* rgn = (int*)alloc((size_t)128 * 4);

  // fused setup: prep + pack1 + packT2 + packT3 + h2p halo
  {
    int nhalo = C * 8 * 260;
    int total = 753664 + nhalo;
    int nblk = 1 + (total + 255) / 256;
    hipLaunchKernelGGL(setup_k, dim3(nblk), dim3(256), 0, stream,
                       rgn_raw, rgn, feat, w1, w1p, w2, w2p, w3, w3p, h2p, nhalo);
  }

  for (int b0 = 0; b0 < 128; b0 += C) {
    // fused conv1+conv2: grid (x-half, 16 row-groups, sample)
    hipLaunchKernelGGL(conv12_k, dim3(2, 16, C), dim3(256), 0, stream,
                       img, w1p, b1, w2p, b2, rgn, h2p, b0);
    // conv3 double-buffered: 8 row-group blocks per sample, 256 thr
    hipLaunchKernelGGL(conv3d_k, dim3(8, C), dim3(256), 0, stream,
                       h2p, w3p, b3, rgn, feat, b0);
  }
  hipLaunchKernelGGL(head_k, dim3(1), dim3(256), 0, stream, feat, fw, fb, rgn, out);
}